// Round 5
// baseline (1733.972 us; speedup 1.0000x reference)
//
#include <hip/hip_runtime.h>
#include <hip/hip_bf16.h>

typedef __attribute__((ext_vector_type(8))) short short8;
typedef __attribute__((ext_vector_type(4))) float f32x4;

#define MFMA16(a, b, c) __builtin_amdgcn_mfma_f32_16x16x32_bf16((a), (b), (c), 0, 0, 0)

__device__ __forceinline__ unsigned short f2bf(float f) {
  unsigned int u = __builtin_bit_cast(unsigned int, f);
  u += 0x7fffu + ((u >> 16) & 1u);   // RNE
  return (unsigned short)(u >> 16);
}
__device__ __forceinline__ float bf2f(unsigned short s) {
  unsigned int u = ((unsigned int)s) << 16;
  return __builtin_bit_cast(float, u);
}
// Fast gate nonlinearities: v_exp_f32 + v_rcp_f32 (validated R2: absmax 3.9e-3)
__device__ __forceinline__ float sigm(float x) {
  return __builtin_amdgcn_rcpf(1.0f + __builtin_amdgcn_exp2f(-1.44269504f * x));
}
__device__ __forceinline__ float tanh_(float x) {
  return 1.0f - 2.0f * __builtin_amdgcn_rcpf(1.0f + __builtin_amdgcn_exp2f(2.88539008f * x));
}
__device__ __forceinline__ f32x4 splat4(float v) {
  f32x4 r; r[0] = v; r[1] = v; r[2] = v; r[3] = v; return r;
}

// ---------------------------------------------------------------------------
// Prep: swizzle weights into MFMA B-fragment-linear bf16 layout.
// W0f[nt][kc<5][lane][8] : B[k=kc*32+(lane>>4)*8+j][n=nt*16+(lane&15)]
//   layer0 k: [0,28)=w_ih_l0, [28,32)=0 pad, [32,160)=w_hh_l0
// W1f[nt][kc<8][lane][8] : k: [0,128)=w_ih_l1, [128,256)=w_hh_l1
// ---------------------------------------------------------------------------
__global__ void prep_weights(const float* __restrict__ w_ih_l0, const float* __restrict__ w_hh_l0,
                             const float* __restrict__ w_ih_l1, const float* __restrict__ w_hh_l1,
                             unsigned short* __restrict__ W0f, unsigned short* __restrict__ W1f) {
  int tid = blockIdx.x * blockDim.x + threadIdx.x;
  if (tid < 32 * 5 * 64) {
    int nt = tid / 320, rem = tid % 320;
    int kc = rem / 64, lane = rem % 64;
    int g = nt * 16 + (lane & 15);
    int k0 = kc * 32 + (lane >> 4) * 8;
#pragma unroll
    for (int j = 0; j < 8; ++j) {
      int k = k0 + j;
      float val;
      if (k < 28) val = w_ih_l0[g * 28 + k];
      else if (k < 32) val = 0.0f;
      else val = w_hh_l0[g * 128 + (k - 32)];
      W0f[tid * 8 + j] = f2bf(val);
    }
  } else if (tid < 32 * 5 * 64 + 32 * 8 * 64) {
    int id = tid - 32 * 5 * 64;
    int nt = id / 512, rem = id % 512;
    int kc = rem / 64, lane = rem % 64;
    int g = nt * 16 + (lane & 15);
    int k0 = kc * 32 + (lane >> 4) * 8;
#pragma unroll
    for (int j = 0; j < 8; ++j) {
      int k = k0 + j;
      float val = (k < 128) ? w_ih_l1[g * 128 + k] : w_hh_l1[g * 128 + (k - 128)];
      W1f[id * 8 + j] = f2bf(val);
    }
  }
}

// ---------------------------------------------------------------------------
// Fused 2-layer LSTM. 256 blocks x 1024 threads (16 waves). Block owns 64
// batch rows for all 28 timesteps. Wave wv: n-slice = wv&7 (h-cols
// [16*(wv&7), +16) of all 4 gates), m-group = wv>>3 (2 of 4 m-tiles).
// Per-wave VGPR demand ~105.
//
// REGISTER-BUDGET CONTROL (R1/R2/R4 evidence): the allocator targets the max
// occupancy LDS permits. 64 KiB LDS -> 2 WG/CU -> 32 waves/CU -> 64-VGPR
// budget -> ~40 spilled regs/wave -> 4.3 GB scratch HBM traffic (the entire
// R2/R4 bottleneck). Padding static LDS to 96 KiB forces 1 WG/CU -> 16
// waves/CU -> 128-VGPR budget -> no spill. Grid is 256 = 1 block/CU anyway,
// so the occupancy "loss" is free. __launch_bounds__ arg2 is IGNORED by this
// toolchain (R4 == R2 counters), so LDS is the only lever.
// c stays in registers (MFMA C/D layout); h double-buffered in swizzled LDS.
// ---------------------------------------------------------------------------
#define HBUF_SZ 12288   // 8192 used + 4096 pad; 2*2*12288*2B = 96 KiB total
__global__ __launch_bounds__(1024) void lstm_fused(
    const float* __restrict__ x,
    const float* __restrict__ b_ih_l0, const float* __restrict__ b_hh_l0,
    const float* __restrict__ b_ih_l1, const float* __restrict__ b_hh_l1,
    const float* __restrict__ fc_w, const float* __restrict__ fc_b,
    const unsigned short* __restrict__ W0f, const unsigned short* __restrict__ W1f,
    float* __restrict__ out) {
  // element (row,col): hbuf[layer][p][row*128 + (((col>>3) ^ (row&15))<<3) + (col&7)]
  __shared__ unsigned short hbuf[2][2][HBUF_SZ];

  const int tid = (int)threadIdx.x;
  const int wv = tid >> 6;          // wave 0..15
  const int ws = wv & 7;            // n-slice
  const int mg = (wv >> 3) * 2;     // first m-tile of this wave's pair
  const int lane = tid & 63;
  const int lr = lane & 15;         // A: m-row / B: n-col / D: col
  const int lq = lane >> 4;         // k-quad / D row group
  const int b0 = (int)blockIdx.x * 64;

  for (int i = tid; i < 64 * 128; i += 1024) {
    hbuf[0][0][i] = 0; hbuf[0][1][i] = 0; hbuf[1][0][i] = 0; hbuf[1][1][i] = 0;
  }

  float bias0v[4], bias1v[4];
#pragma unroll
  for (int q = 0; q < 4; ++q) {
    int g = q * 128 + ws * 16 + lr;
    bias0v[q] = b_ih_l0[g] + b_hh_l0[g];
    bias1v[q] = b_ih_l1[g] + b_hh_l1[g];
  }

  float c0s[2][4], c1s[2][4];   // [mloc][r]
#pragma unroll
  for (int m = 0; m < 2; ++m)
#pragma unroll
    for (int r = 0; r < 4; ++r) { c0s[m][r] = 0.0f; c1s[m][r] = 0.0f; }

  __syncthreads();

  for (int t = 0; t < 28; ++t) {
    const int p = t & 1;
    const unsigned short* h0r = hbuf[0][1 - p];
    unsigned short* h0w = hbuf[0][p];
    const unsigned short* h1r = hbuf[1][1 - p];
    unsigned short* h1w = hbuf[1][p];
    const bool last = (t == 27);

    // ---------------- layer 0: gates = [x_t | h0(t-1)] @ W0^T + b ----------
    f32x4 acc[2][4];   // [mloc][q]
#pragma unroll
    for (int m = 0; m < 2; ++m)
#pragma unroll
      for (int q = 0; q < 4; ++q) acc[m][q] = splat4(bias0v[q]);

    short8 ax[2];   // x A-fragments (K-chunk 0, 28 real + 4 zero cols)
#pragma unroll
    for (int m = 0; m < 2; ++m) {
      const float* xp = x + (size_t)(b0 + (mg + m) * 16 + lr) * 784 + t * 28 + lq * 8;
      f32x4 u0 = *(const f32x4*)xp;
      f32x4 u1 = {0.0f, 0.0f, 0.0f, 0.0f};
      if (lq < 3) u1 = *(const f32x4*)(xp + 4);   // lq==3: cols 28..31 are pad
      short8 s;
      s[0] = (short)f2bf(u0[0]); s[1] = (short)f2bf(u0[1]);
      s[2] = (short)f2bf(u0[2]); s[3] = (short)f2bf(u0[3]);
      s[4] = (short)f2bf(u1[0]); s[5] = (short)f2bf(u1[1]);
      s[6] = (short)f2bf(u1[2]); s[7] = (short)f2bf(u1[3]);
      ax[m] = s;
    }

#pragma unroll
    for (int kc = 0; kc < 5; ++kc) {
      short8 bq[4];
#pragma unroll
      for (int q = 0; q < 4; ++q)
        bq[q] = *(const short8*)(W0f + (size_t)(((q * 8 + ws) * 5 + kc) * 64 + lane) * 8);
      short8 am[2];
#pragma unroll
      for (int m = 0; m < 2; ++m) {
        if (kc == 0) am[m] = ax[m];
        else am[m] = *(const short8*)(h0r + ((mg + m) * 16 + lr) * 128 + ((((kc - 1) * 4 + lq) ^ lr) << 3));
      }
#pragma unroll
      for (int m = 0; m < 2; ++m)
#pragma unroll
        for (int q = 0; q < 4; ++q) acc[m][q] = MFMA16(am[m], bq[q], acc[m][q]);
    }

#pragma unroll
    for (int m = 0; m < 2; ++m)
#pragma unroll
      for (int r = 0; r < 4; ++r) {
        float gi = acc[m][0][r], gf = acc[m][1][r], gg = acc[m][2][r], go = acc[m][3][r];
        float c = sigm(gf) * c0s[m][r] + sigm(gi) * tanh_(gg);
        float h = sigm(go) * tanh_(c);
        c0s[m][r] = c;
        int row = (mg + m) * 16 + lq * 4 + r;
        int col = ws * 16 + lr;
        h0w[row * 128 + (((col >> 3) ^ (row & 15)) << 3) + (col & 7)] = f2bf(h);
        if (last) {
          out[163840 + (size_t)(b0 + row) * 128 + col] = h;       // h_n layer 0
          out[4358144 + (size_t)(b0 + row) * 128 + col] = c;      // c_n layer 0
        }
      }

    __syncthreads();   // h0(t) visible to all waves

    // ---------------- layer 1: gates = [h0(t) | h1(t-1)] @ W1^T + b --------
#pragma unroll
    for (int m = 0; m < 2; ++m)
#pragma unroll
      for (int q = 0; q < 4; ++q) acc[m][q] = splat4(bias1v[q]);

#pragma unroll
    for (int kc = 0; kc < 8; ++kc) {
      short8 bq[4];
#pragma unroll
      for (int q = 0; q < 4; ++q)
        bq[q] = *(const short8*)(W1f + (size_t)(((q * 8 + ws) * 8 + kc) * 64 + lane) * 8);
      const unsigned short* src = (kc < 4) ? h0w : h1r;
      const int kcl = (kc < 4) ? kc : (kc - 4);
      short8 am[2];
#pragma unroll
      for (int m = 0; m < 2; ++m)
        am[m] = *(const short8*)(src + ((mg + m) * 16 + lr) * 128 + (((kcl * 4 + lq) ^ lr) << 3));
#pragma unroll
      for (int m = 0; m < 2; ++m)
#pragma unroll
        for (int q = 0; q < 4; ++q) acc[m][q] = MFMA16(am[m], bq[q], acc[m][q]);
    }

#pragma unroll
    for (int m = 0; m < 2; ++m)
#pragma unroll
      for (int r = 0; r < 4; ++r) {
        float gi = acc[m][0][r], gf = acc[m][1][r], gg = acc[m][2][r], go = acc[m][3][r];
        float c = sigm(gf) * c1s[m][r] + sigm(gi) * tanh_(gg);
        float h = sigm(go) * tanh_(c);
        c1s[m][r] = c;
        int row = (mg + m) * 16 + lq * 4 + r;
        int col = ws * 16 + lr;
        h1w[row * 128 + (((col >> 3) ^ (row & 15)) << 3) + (col & 7)] = f2bf(h);
        if (last) {
          out[163840 + 2097152 + (size_t)(b0 + row) * 128 + col] = h;   // h_n layer 1
          out[4358144 + 2097152 + (size_t)(b0 + row) * 128 + col] = c;  // c_n layer 1
        }
      }

    __syncthreads();   // h1(t) visible; protects double-buffer WAR
  }

  // ---------------- logits = h1(27) @ fc_w^T + fc_b ------------------------
  const unsigned short* h1f = hbuf[1][1];   // t=27 parity
  if (tid < 640) {
    int bl = tid / 10, o = tid % 10;
    float s = fc_b[o];
#pragma unroll
    for (int kc8 = 0; kc8 < 16; ++kc8) {
      short8 hv = *(const short8*)(h1f + bl * 128 + ((kc8 ^ (bl & 15)) << 3));
      const float* wp = fc_w + o * 128 + kc8 * 8;
#pragma unroll
      for (int j = 0; j < 8; ++j) s += bf2f((unsigned short)hv[j]) * wp[j];
    }
    out[(size_t)(b0 + bl) * 10 + o] = s;
  }
}

extern "C" void kernel_launch(void* const* d_in, const int* in_sizes, int n_in,
                              void* d_out, int out_size, void* d_ws, size_t ws_size,
                              hipStream_t stream) {
  const float* x       = (const float*)d_in[0];
  const float* w_ih_l0 = (const float*)d_in[1];
  const float* w_hh_l0 = (const float*)d_in[2];
  const float* b_ih_l0 = (const float*)d_in[3];
  const float* b_hh_l0 = (const float*)d_in[4];
  const float* w_ih_l1 = (const float*)d_in[5];
  const float* w_hh_l1 = (const float*)d_in[6];
  const float* b_ih_l1 = (const float*)d_in[7];
  const float* b_hh_l1 = (const float*)d_in[8];
  const float* fc_w    = (const float*)d_in[9];
  const float* fc_b    = (const float*)d_in[10];

  unsigned short* W0f = (unsigned short*)d_ws;            // 32*5*64*8 = 81920 ush
  unsigned short* W1f = W0f + 32 * 5 * 64 * 8;            // 32*8*64*8 = 131072 ush
  float* out = (float*)d_out;

  hipLaunchKernelGGL(prep_weights, dim3(104), dim3(256), 0, stream,
                     w_ih_l0, w_hh_l0, w_ih_l1, w_hh_l1, W0f, W1f);
  hipLaunchKernelGGL(lstm_fused, dim3(256), dim3(1024), 0, stream,
                     x, b_ih_l0, b_hh_l0, b_ih_l1, b_hh_l1, fc_w, fc_b, W0f, W1f, out);
}

// Round 6
// 870.415 us; speedup vs baseline: 1.9921x; 1.9921x over previous
//
#include <hip/hip_runtime.h>
#include <hip/hip_bf16.h>

typedef __attribute__((ext_vector_type(8))) short short8;
typedef __attribute__((ext_vector_type(4))) float f32x4;

#define MFMA16(a, b, c) __builtin_amdgcn_mfma_f32_16x16x32_bf16((a), (b), (c), 0, 0, 0)

__device__ __forceinline__ unsigned short f2bf(float f) {
  unsigned int u = __builtin_bit_cast(unsigned int, f);
  u += 0x7fffu + ((u >> 16) & 1u);   // RNE
  return (unsigned short)(u >> 16);
}
__device__ __forceinline__ float bf2f(unsigned short s) {
  unsigned int u = ((unsigned int)s) << 16;
  return __builtin_bit_cast(float, u);
}
// Fast gate nonlinearities: v_exp_f32 + v_rcp_f32 (validated R2: absmax 3.9e-3)
__device__ __forceinline__ float sigm(float x) {
  return __builtin_amdgcn_rcpf(1.0f + __builtin_amdgcn_exp2f(-1.44269504f * x));
}
__device__ __forceinline__ float tanh_(float x) {
  return 1.0f - 2.0f * __builtin_amdgcn_rcpf(1.0f + __builtin_amdgcn_exp2f(2.88539008f * x));
}
__device__ __forceinline__ f32x4 splat4(float v) {
  f32x4 r; r[0] = v; r[1] = v; r[2] = v; r[3] = v; return r;
}

// ---------------------------------------------------------------------------
// Prep: swizzle weights into MFMA B-fragment-linear bf16 layout.
// W0f[nt][kc<5][lane][8] : B[k=kc*32+(lane>>4)*8+j][n=nt*16+(lane&15)]
//   layer0 k: [0,28)=w_ih_l0, [28,32)=0 pad, [32,160)=w_hh_l0
// W1f[nt][kc<8][lane][8] : k: [0,128)=w_ih_l1, [128,256)=w_hh_l1
// ---------------------------------------------------------------------------
__global__ void prep_weights(const float* __restrict__ w_ih_l0, const float* __restrict__ w_hh_l0,
                             const float* __restrict__ w_ih_l1, const float* __restrict__ w_hh_l1,
                             unsigned short* __restrict__ W0f, unsigned short* __restrict__ W1f) {
  int tid = blockIdx.x * blockDim.x + threadIdx.x;
  if (tid < 32 * 5 * 64) {
    int nt = tid / 320, rem = tid % 320;
    int kc = rem / 64, lane = rem % 64;
    int g = nt * 16 + (lane & 15);
    int k0 = kc * 32 + (lane >> 4) * 8;
#pragma unroll
    for (int j = 0; j < 8; ++j) {
      int k = k0 + j;
      float val;
      if (k < 28) val = w_ih_l0[g * 28 + k];
      else if (k < 32) val = 0.0f;
      else val = w_hh_l0[g * 128 + (k - 32)];
      W0f[tid * 8 + j] = f2bf(val);
    }
  } else if (tid < 32 * 5 * 64 + 32 * 8 * 64) {
    int id = tid - 32 * 5 * 64;
    int nt = id / 512, rem = id % 512;
    int kc = rem / 64, lane = rem % 64;
    int g = nt * 16 + (lane & 15);
    int k0 = kc * 32 + (lane >> 4) * 8;
#pragma unroll
    for (int j = 0; j < 8; ++j) {
      int k = k0 + j;
      float val = (k < 128) ? w_ih_l1[g * 128 + k] : w_hh_l1[g * 128 + (k - 128)];
      W1f[id * 8 + j] = f2bf(val);
    }
  }
}

// ---------------------------------------------------------------------------
// Fused 2-layer LSTM. 512 blocks x 512 threads (8 waves). Block owns 32 batch
// rows for all 28 timesteps. Wave wv (0..7) = n-slice: h-cols [16wv,16wv+16)
// of all 4 gates, for both m-tiles (rows 0-15, 16-31 of the block).
//
// REGISTER BUDGET (R1/R2/R4/R5 evidence): allocator budgets for 2 WG/CU from
// block size alone — 512-thread blocks get 128 VGPRs/wave, 1024-thread get 64;
// __launch_bounds__ arg2 and LDS size are both IGNORED. So: 512 threads +
// per-wave demand ~110 (acc[2][4]x4=32, c 16, bq 16, am/ax 16, bias 8,
// addr ~20) ≤ 128 -> no scratch spill (spill was 100% of the R1-R5 bottleneck:
// 1.5-4.5 GB HBM scratch traffic).
// LDS: 32 KiB used, padded to 64 KiB so even an LDS-aware heuristic computes
// 2 WG/CU -> same 128 budget. Grid 512 = 2 blocks/CU co-resident (2x64 KiB
// LDS fits 160). c stays in registers (MFMA C/D layout); h double-buffered in
// XOR-swizzled LDS.
// ---------------------------------------------------------------------------
#define HB 8192   // per-buffer stride (4096 used + 4096 pad) -> 4*HB*2B = 64 KiB
__global__ __launch_bounds__(512) void lstm_fused(
    const float* __restrict__ x,
    const float* __restrict__ b_ih_l0, const float* __restrict__ b_hh_l0,
    const float* __restrict__ b_ih_l1, const float* __restrict__ b_hh_l1,
    const float* __restrict__ fc_w, const float* __restrict__ fc_b,
    const unsigned short* __restrict__ W0f, const unsigned short* __restrict__ W1f,
    float* __restrict__ out) {
  // element (row,col): hbuf[layer][p][row*128 + (((col>>3) ^ (row&15))<<3) + (col&7)]
  __shared__ unsigned short hbuf[2][2][HB];

  const int tid = (int)threadIdx.x;
  const int wv = tid >> 6;          // wave 0..7 = n-slice
  const int lane = tid & 63;
  const int lr = lane & 15;         // A: m-row / B: n-col / D: col
  const int lq = lane >> 4;         // k-quad / D row group
  const int b0 = (int)blockIdx.x * 32;

  for (int i = tid; i < 32 * 128; i += 512) {
    hbuf[0][0][i] = 0; hbuf[0][1][i] = 0; hbuf[1][0][i] = 0; hbuf[1][1][i] = 0;
  }

  float bias0v[4], bias1v[4];
#pragma unroll
  for (int q = 0; q < 4; ++q) {
    int g = q * 128 + wv * 16 + lr;
    bias0v[q] = b_ih_l0[g] + b_hh_l0[g];
    bias1v[q] = b_ih_l1[g] + b_hh_l1[g];
  }

  float c0s[2][4], c1s[2][4];   // [m][r]
#pragma unroll
  for (int m = 0; m < 2; ++m)
#pragma unroll
    for (int r = 0; r < 4; ++r) { c0s[m][r] = 0.0f; c1s[m][r] = 0.0f; }

  __syncthreads();

  for (int t = 0; t < 28; ++t) {
    const int p = t & 1;
    const unsigned short* h0r = hbuf[0][1 - p];
    unsigned short* h0w = hbuf[0][p];
    const unsigned short* h1r = hbuf[1][1 - p];
    unsigned short* h1w = hbuf[1][p];
    const bool last = (t == 27);

    // ---------------- layer 0: gates = [x_t | h0(t-1)] @ W0^T + b ----------
    f32x4 acc[2][4];   // [m][q]
#pragma unroll
    for (int m = 0; m < 2; ++m)
#pragma unroll
      for (int q = 0; q < 4; ++q) acc[m][q] = splat4(bias0v[q]);

    short8 ax[2];   // x A-fragments (K-chunk 0, 28 real + 4 zero cols)
#pragma unroll
    for (int m = 0; m < 2; ++m) {
      const float* xp = x + (size_t)(b0 + m * 16 + lr) * 784 + t * 28 + lq * 8;
      f32x4 u0 = *(const f32x4*)xp;
      f32x4 u1 = {0.0f, 0.0f, 0.0f, 0.0f};
      if (lq < 3) u1 = *(const f32x4*)(xp + 4);   // lq==3: cols 28..31 are pad
      short8 s;
      s[0] = (short)f2bf(u0[0]); s[1] = (short)f2bf(u0[1]);
      s[2] = (short)f2bf(u0[2]); s[3] = (short)f2bf(u0[3]);
      s[4] = (short)f2bf(u1[0]); s[5] = (short)f2bf(u1[1]);
      s[6] = (short)f2bf(u1[2]); s[7] = (short)f2bf(u1[3]);
      ax[m] = s;
    }

#pragma unroll
    for (int kc = 0; kc < 5; ++kc) {
      short8 bq[4];
#pragma unroll
      for (int q = 0; q < 4; ++q)
        bq[q] = *(const short8*)(W0f + (size_t)(((q * 8 + wv) * 5 + kc) * 64 + lane) * 8);
      short8 am[2];
#pragma unroll
      for (int m = 0; m < 2; ++m) {
        if (kc == 0) am[m] = ax[m];
        else am[m] = *(const short8*)(h0r + (m * 16 + lr) * 128 + ((((kc - 1) * 4 + lq) ^ lr) << 3));
      }
#pragma unroll
      for (int m = 0; m < 2; ++m)
#pragma unroll
        for (int q = 0; q < 4; ++q) acc[m][q] = MFMA16(am[m], bq[q], acc[m][q]);
    }

#pragma unroll
    for (int m = 0; m < 2; ++m)
#pragma unroll
      for (int r = 0; r < 4; ++r) {
        float gi = acc[m][0][r], gf = acc[m][1][r], gg = acc[m][2][r], go = acc[m][3][r];
        float c = sigm(gf) * c0s[m][r] + sigm(gi) * tanh_(gg);
        float h = sigm(go) * tanh_(c);
        c0s[m][r] = c;
        int row = m * 16 + lq * 4 + r;
        int col = wv * 16 + lr;
        h0w[row * 128 + (((col >> 3) ^ (row & 15)) << 3) + (col & 7)] = f2bf(h);
        if (last) {
          out[163840 + (size_t)(b0 + row) * 128 + col] = h;       // h_n layer 0
          out[4358144 + (size_t)(b0 + row) * 128 + col] = c;      // c_n layer 0
        }
      }

    __syncthreads();   // h0(t) visible to all waves

    // ---------------- layer 1: gates = [h0(t) | h1(t-1)] @ W1^T + b --------
#pragma unroll
    for (int m = 0; m < 2; ++m)
#pragma unroll
      for (int q = 0; q < 4; ++q) acc[m][q] = splat4(bias1v[q]);

#pragma unroll
    for (int kc = 0; kc < 8; ++kc) {
      short8 bq[4];
#pragma unroll
      for (int q = 0; q < 4; ++q)
        bq[q] = *(const short8*)(W1f + (size_t)(((q * 8 + wv) * 8 + kc) * 64 + lane) * 8);
      const unsigned short* src = (kc < 4) ? h0w : h1r;
      const int kcl = (kc < 4) ? kc : (kc - 4);
      short8 am[2];
#pragma unroll
      for (int m = 0; m < 2; ++m)
        am[m] = *(const short8*)(src + (m * 16 + lr) * 128 + (((kcl * 4 + lq) ^ lr) << 3));
#pragma unroll
      for (int m = 0; m < 2; ++m)
#pragma unroll
        for (int q = 0; q < 4; ++q) acc[m][q] = MFMA16(am[m], bq[q], acc[m][q]);
    }

#pragma unroll
    for (int m = 0; m < 2; ++m)
#pragma unroll
      for (int r = 0; r < 4; ++r) {
        float gi = acc[m][0][r], gf = acc[m][1][r], gg = acc[m][2][r], go = acc[m][3][r];
        float c = sigm(gf) * c1s[m][r] + sigm(gi) * tanh_(gg);
        float h = sigm(go) * tanh_(c);
        c1s[m][r] = c;
        int row = m * 16 + lq * 4 + r;
        int col = wv * 16 + lr;
        h1w[row * 128 + (((col >> 3) ^ (row & 15)) << 3) + (col & 7)] = f2bf(h);
        if (last) {
          out[163840 + 2097152 + (size_t)(b0 + row) * 128 + col] = h;   // h_n layer 1
          out[4358144 + 2097152 + (size_t)(b0 + row) * 128 + col] = c;  // c_n layer 1
        }
      }

    __syncthreads();   // h1(t) visible; protects double-buffer WAR
  }

  // ---------------- logits = h1(27) @ fc_w^T + fc_b ------------------------
  const unsigned short* h1f = hbuf[1][1];   // t=27 parity
  if (tid < 320) {
    int bl = tid / 10, o = tid % 10;
    float s = fc_b[o];
#pragma unroll
    for (int kc8 = 0; kc8 < 16; ++kc8) {
      short8 hv = *(const short8*)(h1f + bl * 128 + ((kc8 ^ (bl & 15)) << 3));
      const float* wp = fc_w + o * 128 + kc8 * 8;
#pragma unroll
      for (int j = 0; j < 8; ++j) s += bf2f((unsigned short)hv[j]) * wp[j];
    }
    out[(size_t)(b0 + bl) * 10 + o] = s;
  }
}

extern "C" void kernel_launch(void* const* d_in, const int* in_sizes, int n_in,
                              void* d_out, int out_size, void* d_ws, size_t ws_size,
                              hipStream_t stream) {
  const float* x       = (const float*)d_in[0];
  const float* w_ih_l0 = (const float*)d_in[1];
  const float* w_hh_l0 = (const float*)d_in[2];
  const float* b_ih_l0 = (const float*)d_in[3];
  const float* b_hh_l0 = (const float*)d_in[4];
  const float* w_ih_l1 = (const float*)d_in[5];
  const float* w_hh_l1 = (const float*)d_in[6];
  const float* b_ih_l1 = (const float*)d_in[7];
  const float* b_hh_l1 = (const float*)d_in[8];
  const float* fc_w    = (const float*)d_in[9];
  const float* fc_b    = (const float*)d_in[10];

  unsigned short* W0f = (unsigned short*)d_ws;            // 32*5*64*8 = 81920 ush
  unsigned short* W1f = W0f + 32 * 5 * 64 * 8;            // 32*8*64*8 = 131072 ush
  float* out = (float*)d_out;

  hipLaunchKernelGGL(prep_weights, dim3(104), dim3(256), 0, stream,
                     w_ih_l0, w_hh_l0, w_ih_l1, w_hh_l1, W0f, W1f);
  hipLaunchKernelGGL(lstm_fused, dim3(512), dim3(512), 0, stream,
                     x, b_ih_l0, b_hh_l0, b_ih_l1, b_hh_l1, fc_w, fc_b, W0f, W1f, out);
}

// Round 7
// 463.431 us; speedup vs baseline: 3.7416x; 1.8782x over previous
//
#include <hip/hip_runtime.h>
#include <hip/hip_bf16.h>

typedef __attribute__((ext_vector_type(8))) short short8;
typedef __attribute__((ext_vector_type(4))) float f32x4;

#define MFMA16(a, b, c) __builtin_amdgcn_mfma_f32_16x16x32_bf16((a), (b), (c), 0, 0, 0)

__device__ __forceinline__ unsigned short f2bf(float f) {
  unsigned int u = __builtin_bit_cast(unsigned int, f);
  u += 0x7fffu + ((u >> 16) & 1u);   // RNE
  return (unsigned short)(u >> 16);
}
__device__ __forceinline__ float bf2f(unsigned short s) {
  unsigned int u = ((unsigned int)s) << 16;
  return __builtin_bit_cast(float, u);
}
// Fast gate nonlinearities: v_exp_f32 + v_rcp_f32 (validated R2: absmax 3.9e-3)
__device__ __forceinline__ float sigm(float x) {
  return __builtin_amdgcn_rcpf(1.0f + __builtin_amdgcn_exp2f(-1.44269504f * x));
}
__device__ __forceinline__ float tanh_(float x) {
  return 1.0f - 2.0f * __builtin_amdgcn_rcpf(1.0f + __builtin_amdgcn_exp2f(2.88539008f * x));
}
__device__ __forceinline__ f32x4 splat4(float v) {
  f32x4 r; r[0] = v; r[1] = v; r[2] = v; r[3] = v; return r;
}

// ---------------------------------------------------------------------------
// Prep: swizzle weights into MFMA B-fragment-linear bf16 layout.
// W0f[nt][kc<5][lane][8] : B[k=kc*32+(lane>>4)*8+j][n=nt*16+(lane&15)]
//   layer0 k: [0,28)=w_ih_l0, [28,32)=0 pad, [32,160)=w_hh_l0
// W1f[nt][kc<8][lane][8] : k: [0,128)=w_ih_l1, [128,256)=w_hh_l1
// ---------------------------------------------------------------------------
__global__ void prep_weights(const float* __restrict__ w_ih_l0, const float* __restrict__ w_hh_l0,
                             const float* __restrict__ w_ih_l1, const float* __restrict__ w_hh_l1,
                             unsigned short* __restrict__ W0f, unsigned short* __restrict__ W1f) {
  int tid = blockIdx.x * blockDim.x + threadIdx.x;
  if (tid < 32 * 5 * 64) {
    int nt = tid / 320, rem = tid % 320;
    int kc = rem / 64, lane = rem % 64;
    int g = nt * 16 + (lane & 15);
    int k0 = kc * 32 + (lane >> 4) * 8;
#pragma unroll
    for (int j = 0; j < 8; ++j) {
      int k = k0 + j;
      float val;
      if (k < 28) val = w_ih_l0[g * 28 + k];
      else if (k < 32) val = 0.0f;
      else val = w_hh_l0[g * 128 + (k - 32)];
      W0f[tid * 8 + j] = f2bf(val);
    }
  } else if (tid < 32 * 5 * 64 + 32 * 8 * 64) {
    int id = tid - 32 * 5 * 64;
    int nt = id / 512, rem = id % 512;
    int kc = rem / 64, lane = rem % 64;
    int g = nt * 16 + (lane & 15);
    int k0 = kc * 32 + (lane >> 4) * 8;
#pragma unroll
    for (int j = 0; j < 8; ++j) {
      int k = k0 + j;
      float val = (k < 128) ? w_ih_l1[g * 128 + k] : w_hh_l1[g * 128 + (k - 128)];
      W1f[id * 8 + j] = f2bf(val);
    }
  }
}

// ---------------------------------------------------------------------------
// Fused 2-layer LSTM. 512 blocks x 512 threads (8 waves). Block owns 32 batch
// rows for all 28 timesteps. Wave wv (0..7) = n-slice: h-cols [16wv,16wv+16)
// of all 4 gates, for both m-tiles (rows 0-15, 16-31).
//
// REGISTER BUDGET (R1-R6): 512-thread blocks -> 128-VGPR budget (block size is
// the ONLY lever; launch_bounds arg2 & LDS size are ignored). R6 showed the
// budget alone isn't enough: fully-unrolled kc loops let the scheduler hoist
// all 13 iterations' weight loads (208 VGPRs) -> spill (1.65 GB excess FETCH).
// Fix here: peel kc=0, #pragma unroll 2 on all weight loops, split layer 1
// into two loops (h0w then h1r) to kill the per-iteration src select. Live set
// ~115 VGPRs: acc 32 + bq 2x16 + am 2x8 + c 16 + bias 8 + persistents ~20.
// c stays in registers (MFMA C/D layout); h double-buffered in swizzled LDS.
// ---------------------------------------------------------------------------
#define HB 8192   // per-buffer stride (4096 used + 4096 pad) -> 4*HB*2B = 64 KiB
__global__ __launch_bounds__(512) void lstm_fused(
    const float* __restrict__ x,
    const float* __restrict__ b_ih_l0, const float* __restrict__ b_hh_l0,
    const float* __restrict__ b_ih_l1, const float* __restrict__ b_hh_l1,
    const float* __restrict__ fc_w, const float* __restrict__ fc_b,
    const unsigned short* __restrict__ W0f, const unsigned short* __restrict__ W1f,
    float* __restrict__ out) {
  // element (row,col): hbuf[layer][p][row*128 + (((col>>3) ^ (row&15))<<3) + (col&7)]
  __shared__ unsigned short hbuf[2][2][HB];

  const int tid = (int)threadIdx.x;
  const int wv = tid >> 6;          // wave 0..7 = n-slice
  const int lane = tid & 63;
  const int lr = lane & 15;         // A: m-row / B: n-col / D: col
  const int lq = lane >> 4;         // k-quad / D row group
  const int b0 = (int)blockIdx.x * 32;

  for (int i = tid; i < 32 * 128; i += 512) {
    hbuf[0][0][i] = 0; hbuf[0][1][i] = 0; hbuf[1][0][i] = 0; hbuf[1][1][i] = 0;
  }

  float bias0v[4], bias1v[4];
#pragma unroll
  for (int q = 0; q < 4; ++q) {
    int g = q * 128 + wv * 16 + lr;
    bias0v[q] = b_ih_l0[g] + b_hh_l0[g];
    bias1v[q] = b_ih_l1[g] + b_hh_l1[g];
  }

  float c0s[2][4], c1s[2][4];   // [m][r]
#pragma unroll
  for (int m = 0; m < 2; ++m)
#pragma unroll
    for (int r = 0; r < 4; ++r) { c0s[m][r] = 0.0f; c1s[m][r] = 0.0f; }

  __syncthreads();

  for (int t = 0; t < 28; ++t) {
    const int p = t & 1;
    const unsigned short* h0r = hbuf[0][1 - p];
    unsigned short* h0w = hbuf[0][p];
    const unsigned short* h1r = hbuf[1][1 - p];
    unsigned short* h1w = hbuf[1][p];
    const bool last = (t == 27);

    // ---------------- layer 0: gates = [x_t | h0(t-1)] @ W0^T + b ----------
    f32x4 acc[2][4];   // [m][q]
#pragma unroll
    for (int m = 0; m < 2; ++m)
#pragma unroll
      for (int q = 0; q < 4; ++q) acc[m][q] = splat4(bias0v[q]);

    // kc = 0 (peeled): A = x_t fragment (28 real cols + 4 zero pad)
    {
      short8 ax[2];
#pragma unroll
      for (int m = 0; m < 2; ++m) {
        const float* xp = x + (size_t)(b0 + m * 16 + lr) * 784 + t * 28 + lq * 8;
        f32x4 u0 = *(const f32x4*)xp;
        f32x4 u1 = {0.0f, 0.0f, 0.0f, 0.0f};
        if (lq < 3) u1 = *(const f32x4*)(xp + 4);   // lq==3: cols 28..31 are pad
        short8 s;
        s[0] = (short)f2bf(u0[0]); s[1] = (short)f2bf(u0[1]);
        s[2] = (short)f2bf(u0[2]); s[3] = (short)f2bf(u0[3]);
        s[4] = (short)f2bf(u1[0]); s[5] = (short)f2bf(u1[1]);
        s[6] = (short)f2bf(u1[2]); s[7] = (short)f2bf(u1[3]);
        ax[m] = s;
      }
      short8 bq[4];
#pragma unroll
      for (int q = 0; q < 4; ++q)
        bq[q] = *(const short8*)(W0f + (size_t)(((q * 8 + wv) * 5 + 0) * 64 + lane) * 8);
#pragma unroll
      for (int m = 0; m < 2; ++m)
#pragma unroll
        for (int q = 0; q < 4; ++q) acc[m][q] = MFMA16(ax[m], bq[q], acc[m][q]);
    }

    // kc = 1..4: A = h0(t-1) from LDS. unroll 2 bounds the load-hoist window.
#pragma unroll 2
    for (int kc = 1; kc < 5; ++kc) {
      short8 bq[4];
#pragma unroll
      for (int q = 0; q < 4; ++q)
        bq[q] = *(const short8*)(W0f + (size_t)(((q * 8 + wv) * 5 + kc) * 64 + lane) * 8);
      short8 am[2];
#pragma unroll
      for (int m = 0; m < 2; ++m)
        am[m] = *(const short8*)(h0r + (m * 16 + lr) * 128 + ((((kc - 1) * 4 + lq) ^ lr) << 3));
#pragma unroll
      for (int m = 0; m < 2; ++m)
#pragma unroll
        for (int q = 0; q < 4; ++q) acc[m][q] = MFMA16(am[m], bq[q], acc[m][q]);
    }

#pragma unroll
    for (int m = 0; m < 2; ++m)
#pragma unroll
      for (int r = 0; r < 4; ++r) {
        float gi = acc[m][0][r], gf = acc[m][1][r], gg = acc[m][2][r], go = acc[m][3][r];
        float c = sigm(gf) * c0s[m][r] + sigm(gi) * tanh_(gg);
        float h = sigm(go) * tanh_(c);
        c0s[m][r] = c;
        int row = m * 16 + lq * 4 + r;
        int col = wv * 16 + lr;
        h0w[row * 128 + (((col >> 3) ^ (row & 15)) << 3) + (col & 7)] = f2bf(h);
        if (last) {
          out[163840 + (size_t)(b0 + row) * 128 + col] = h;       // h_n layer 0
          out[4358144 + (size_t)(b0 + row) * 128 + col] = c;      // c_n layer 0
        }
      }

    __syncthreads();   // h0(t) visible to all waves

    // ---------------- layer 1: gates = [h0(t) | h1(t-1)] @ W1^T + b --------
#pragma unroll
    for (int m = 0; m < 2; ++m)
#pragma unroll
      for (int q = 0; q < 4; ++q) acc[m][q] = splat4(bias1v[q]);

    // kc = 0..3: A = h0(t)
#pragma unroll 2
    for (int kc = 0; kc < 4; ++kc) {
      short8 bq[4];
#pragma unroll
      for (int q = 0; q < 4; ++q)
        bq[q] = *(const short8*)(W1f + (size_t)(((q * 8 + wv) * 8 + kc) * 64 + lane) * 8);
      short8 am[2];
#pragma unroll
      for (int m = 0; m < 2; ++m)
        am[m] = *(const short8*)(h0w + (m * 16 + lr) * 128 + (((kc * 4 + lq) ^ lr) << 3));
#pragma unroll
      for (int m = 0; m < 2; ++m)
#pragma unroll
        for (int q = 0; q < 4; ++q) acc[m][q] = MFMA16(am[m], bq[q], acc[m][q]);
    }
    // kc = 4..7: A = h1(t-1)
#pragma unroll 2
    for (int kc = 4; kc < 8; ++kc) {
      short8 bq[4];
#pragma unroll
      for (int q = 0; q < 4; ++q)
        bq[q] = *(const short8*)(W1f + (size_t)(((q * 8 + wv) * 8 + kc) * 64 + lane) * 8);
      short8 am[2];
#pragma unroll
      for (int m = 0; m < 2; ++m)
        am[m] = *(const short8*)(h1r + (m * 16 + lr) * 128 + ((((kc - 4) * 4 + lq) ^ lr) << 3));
#pragma unroll
      for (int m = 0; m < 2; ++m)
#pragma unroll
        for (int q = 0; q < 4; ++q) acc[m][q] = MFMA16(am[m], bq[q], acc[m][q]);
    }

#pragma unroll
    for (int m = 0; m < 2; ++m)
#pragma unroll
      for (int r = 0; r < 4; ++r) {
        float gi = acc[m][0][r], gf = acc[m][1][r], gg = acc[m][2][r], go = acc[m][3][r];
        float c = sigm(gf) * c1s[m][r] + sigm(gi) * tanh_(gg);
        float h = sigm(go) * tanh_(c);
        c1s[m][r] = c;
        int row = m * 16 + lq * 4 + r;
        int col = wv * 16 + lr;
        h1w[row * 128 + (((col >> 3) ^ (row & 15)) << 3) + (col & 7)] = f2bf(h);
        if (last) {
          out[163840 + 2097152 + (size_t)(b0 + row) * 128 + col] = h;   // h_n layer 1
          out[4358144 + 2097152 + (size_t)(b0 + row) * 128 + col] = c;  // c_n layer 1
        }
      }

    __syncthreads();   // h1(t) visible; protects double-buffer WAR
  }

  // ---------------- logits = h1(27) @ fc_w^T + fc_b ------------------------
  const unsigned short* h1f = hbuf[1][1];   // t=27 parity
  if (tid < 320) {
    int bl = tid / 10, o = tid % 10;
    float s = fc_b[o];
#pragma unroll
    for (int kc8 = 0; kc8 < 16; ++kc8) {
      short8 hv = *(const short8*)(h1f + bl * 128 + ((kc8 ^ (bl & 15)) << 3));
      const float* wp = fc_w + o * 128 + kc8 * 8;
#pragma unroll
      for (int j = 0; j < 8; ++j) s += bf2f((unsigned short)hv[j]) * wp[j];
    }
    out[(size_t)(b0 + bl) * 10 + o] = s;
  }
}

extern "C" void kernel_launch(void* const* d_in, const int* in_sizes, int n_in,
                              void* d_out, int out_size, void* d_ws, size_t ws_size,
                              hipStream_t stream) {
  const float* x       = (const float*)d_in[0];
  const float* w_ih_l0 = (const float*)d_in[1];
  const float* w_hh_l0 = (const float*)d_in[2];
  const float* b_ih_l0 = (const float*)d_in[3];
  const float* b_hh_l0 = (const float*)d_in[4];
  const float* w_ih_l1 = (const float*)d_in[5];
  const float* w_hh_l1 = (const float*)d_in[6];
  const float* b_ih_l1 = (const float*)d_in[7];
  const float* b_hh_l1 = (const float*)d_in[8];
  const float* fc_w    = (const float*)d_in[9];
  const float* fc_b    = (const float*)d_in[10];

  unsigned short* W0f = (unsigned short*)d_ws;            // 32*5*64*8 = 81920 ush
  unsigned short* W1f = W0f + 32 * 5 * 64 * 8;            // 32*8*64*8 = 131072 ush
  float* out = (float*)d_out;

  hipLaunchKernelGGL(prep_weights, dim3(104), dim3(256), 0, stream,
                     w_ih_l0, w_hh_l0, w_ih_l1, w_hh_l1, W0f, W1f);
  hipLaunchKernelGGL(lstm_fused, dim3(512), dim3(512), 0, stream,
                     x, b_ih_l0, b_hh_l0, b_ih_l1, b_hh_l1, fc_w, fc_b, W0f, W1f, out);
}